// Round 7
// baseline (35.717 us; speedup 1.0000x reference)
//
#include <hip/hip_runtime.h>
#include <cstdint>
#include <cstddef>

// Problem constants (fixed shapes from setup_inputs)
#define NIMG 4096
#define NPOS 196       // 14*14 output positions
#define KPAD 896       // 7 * 128, fp8 features zero-padded 784..895
#define NKT  7         // K tiles of BK=128
#define BM 128
#define BN 128

typedef __attribute__((ext_vector_type(16))) float f32x16;
typedef __attribute__((ext_vector_type(4)))  float f32x4;
typedef __attribute__((ext_vector_type(4)))  int   i32x4;
typedef __attribute__((ext_vector_type(8)))  int   i32x8;

__device__ __forceinline__ void gload_lds16(const void* g, void* lds) {
    __builtin_amdgcn_global_load_lds(
        (const __attribute__((address_space(1))) unsigned int*)g,
        (__attribute__((address_space(3))) unsigned int*)lds, 16, 0, 0);
}

// ---------------- feature kernel: conv 2x2 s2 (1->4ch) + bias, fp8 ----------
// Logical K layout: k = pos*4 + ch (K permutation preserves dot products).
// Stored layout: linear k within each 128-B K-slice, with XOR swizzle of
// 16-B slots keyed by n&7 (bank-spread ds_reads; staging copies stored
// bytes verbatim via linear global_load_lds -> rule #21 satisfied).
__global__ __launch_bounds__(256)
void feat_kernel(const float* __restrict__ imgx,
                 const float* __restrict__ imgy,
                 const float* __restrict__ w,   // [4][1][2][2] flat
                 const float* __restrict__ b,   // [4]
                 unsigned char* __restrict__ fx,
                 unsigned char* __restrict__ fy,
                 float* __restrict__ norms)     // [2*NIMG]: x2 then y2
{
    __shared__ float simg[784];
    __shared__ float partial[4];
    const int gb = blockIdx.x;
    const bool isx = gb < NIMG;
    const int n = isx ? gb : gb - NIMG;
    const int t = threadIdx.x;
    const float* img = isx ? imgx : imgy;
    unsigned char* feat = isx ? fx : fy;

    const float4* ip4 = (const float4*)(img + (size_t)n * 784);
    if (t < 196) ((float4*)simg)[t] = ip4[t];
    __syncthreads();

    float ss = 0.f;
    unsigned pack = 0u;
    if (t < NPOS) {
        const int p = t / 14, q = t % 14;
        const float* px = &simg[p * 56 + q * 2];
        const float a0 = px[0], a1 = px[1], a2 = px[28], a3 = px[29];
        float f[4];
#pragma unroll
        for (int c = 0; c < 4; ++c) {
            f[c] = w[c * 4 + 0] * a0 + w[c * 4 + 1] * a1
                 + w[c * 4 + 2] * a2 + w[c * 4 + 3] * a3 + b[c];
            ss += f[c] * f[c];
        }
        pack = __builtin_amdgcn_cvt_pk_fp8_f32(f[0], f[1], 0, false);
        pack = __builtin_amdgcn_cvt_pk_fp8_f32(f[2], f[3], pack, true);
    }
    if (t < KPAD / 4) {
        const int p  = t * 4;
        const int s3 = (p >> 4) & 7;        // 16-B slot within 128-B slice
        const int pf = (p & ~127) | (((s3 ^ (n & 7)) << 4) | (p & 15));
        *(unsigned*)(feat + (size_t)n * KPAD + pf) = pack;  // zeros if t>=196
    }

#pragma unroll
    for (int off = 32; off > 0; off >>= 1) ss += __shfl_down(ss, off, 64);
    if ((t & 63) == 0) partial[t >> 6] = ss;
    __syncthreads();
    if (t == 0) norms[gb] = partial[0] + partial[1] + partial[2] + partial[3];
}

// ---------------- Gram kernel: 128x128 tile, MX fp8 32x32x64, BK=128 -------
// NT GEMM C = A·B^T with exp(-max(x2+y2-2C,0)) epilogue.
// 4 waves (2M x 2N, wave tile 64x64), double-buffered LDS (64 KB) ->
// 2 blocks resident/CU (grid 1024 = 4 sequential blocks/CU): one block's
// epilogue HBM burst and barrier stalls overlap the other's MFMA (m114).
// Counted vmcnt(8), stage depth 2 K-tiles; stage-overwrite fenced by
// lgkmcnt(0)+barrier before the stage issue.

#define RD_A(BUF) do { \
    _Pragma("unroll") for (int mm = 0; mm < 2; ++mm) \
    _Pragma("unroll") for (int ks = 0; ks < 2; ++ks) { \
        const unsigned char* base = &As[BUF][0] \
            + ((wr * 64 + mm * 32 + r32) << 7); \
        const i32x4 lo  = *(const i32x4*)(base + pxc[ks][0]); \
        const i32x4 hi4 = *(const i32x4*)(base + pxc[ks][1]); \
        af[mm][ks] = __builtin_shufflevector(lo, hi4, 0,1,2,3,4,5,6,7); \
    } } while (0)

#define RD_B(BUF) do { \
    _Pragma("unroll") for (int nn = 0; nn < 2; ++nn) \
    _Pragma("unroll") for (int ks = 0; ks < 2; ++ks) { \
        const unsigned char* base = &Bs[BUF][0] \
            + ((wc * 64 + nn * 32 + r32) << 7); \
        const i32x4 lo  = *(const i32x4*)(base + pxc[ks][0]); \
        const i32x4 hi4 = *(const i32x4*)(base + pxc[ks][1]); \
        bf[nn][ks] = __builtin_shufflevector(lo, hi4, 0,1,2,3,4,5,6,7); \
    } } while (0)

#define MFMA_ALL() do { \
    __builtin_amdgcn_s_setprio(1); \
    _Pragma("unroll") for (int ks = 0; ks < 2; ++ks) \
    _Pragma("unroll") for (int mm = 0; mm < 2; ++mm) \
    _Pragma("unroll") for (int nn = 0; nn < 2; ++nn) \
        acc[mm][nn] = __builtin_amdgcn_mfma_scale_f32_32x32x64_f8f6f4( \
            af[mm][ks], bf[nn][ks], acc[mm][nn], 0, 0, 0, 0x7F, 0, 0x7F); \
    __builtin_amdgcn_s_setprio(0); } while (0)

// stage K-tile at byte offset KO into buffer BUF (8 gload_lds per wave)
#define STAGE(BUF, KO) do { \
    _Pragma("unroll") for (int r = 0; r < 4; ++r) { \
        gload_lds16(Asrc + (KO) + (size_t)r * 8 * KPAD, \
                    &As[BUF][(w << 12) + (r << 10)]); \
        gload_lds16(Bsrc + (KO) + (size_t)r * 8 * KPAD, \
                    &Bs[BUF][(w << 12) + (r << 10)]); \
    } } while (0)

#define BAR() __builtin_amdgcn_s_barrier()
#define LGKM0() do { asm volatile("s_waitcnt lgkmcnt(0)" ::: "memory"); \
                     __builtin_amdgcn_sched_barrier(0); } while (0)
#define VMW(N) asm volatile("s_waitcnt vmcnt(" #N ")" ::: "memory")

__global__ __launch_bounds__(256, 2)
void gram_kernel(const unsigned char* __restrict__ A,  // fx fp8 [NIMG][KPAD]
                 const unsigned char* __restrict__ B,  // fy fp8 [NIMG][KPAD]
                 const float* __restrict__ x2,         // [NIMG]
                 const float* __restrict__ y2,         // [NIMG]
                 float* __restrict__ out)              // [NIMG][NIMG]
{
    __shared__ __align__(16) unsigned char As[2][BM * 128];  // 32 KB
    __shared__ __align__(16) unsigned char Bs[2][BN * 128];  // 32 KB

    const int t    = threadIdx.x;
    const int lane = t & 63;
    const int w    = t >> 6;          // wave 0..3
    const int wr   = w >> 1;          // wave row 0..1
    const int wc   = w & 1;           // wave col 0..1

    // XCD-aware bijective mapping: 1024 blocks, 8 XCDs, per-XCD 16x8 chunk
    // (working set ~2.7 MB < 4 MB L2/XCD)
    const int xb = blockIdx.x & 7, cb = blockIdx.x >> 3;  // cb in [0,128)
    const int bm = ((xb & 1) << 4) | (cb & 15);           // [0,32)
    const int bn = ((xb >> 1) << 3) | (cb >> 4);          // [0,32)
    const int bRow = bm * BM;
    const int bCol = bn * BN;

    f32x16 acc[2][2] = {};       // [mm][nn], 64 regs
    i32x8 af[2][2], bf[2][2];    // [mm|nn][ks]

    // fragment-read constants (32x32 f8f6f4: row/col = lane&31,
    // lane covers 32 contiguous k-bytes at k = (lane>>5)*32 + ks*64)
    const int r32 = lane & 31;
    const int hi  = lane >> 5;
    const int f7  = r32 & 7;
    int pxc[2][2];
#pragma unroll
    for (int ks = 0; ks < 2; ++ks)
#pragma unroll
        for (int bb = 0; bb < 2; ++bb)
            pxc[ks][bb] = (((ks * 4) | (hi * 2) | bb) ^ f7) << 4;

    // staging: wave w covers rows w*32 + r*8 + (lane>>3), 16-B slot lane&7;
    // stored layout is pre-swizzled -> verbatim linear copy.
    const int lr = lane >> 3;
    const unsigned char* Asrc = A + (size_t)(bRow + w * 32 + lr) * KPAD
                                  + (lane & 7) * 16;
    const unsigned char* Bsrc = B + (size_t)(bCol + w * 32 + lr) * KPAD
                                  + (lane & 7) * 16;

    // prologue: stage tile0 -> buf0, tile1 -> buf1; counted wait on tile0
    STAGE(0, 0);
    STAGE(1, 128);
    VMW(8);
    BAR();

    for (int kt = 0; kt < NKT; ++kt) {
        const int c = kt & 1;
        RD_A(c); RD_B(c);
        LGKM0();                       // all waves' reads of buf c complete...
        if (kt < 6) BAR();             // ...before anyone overwrites it
        if (kt + 2 < NKT) STAGE(c, (kt + 2) * 128);
        MFMA_ALL();
        if (kt < 6) {
            if (kt + 2 < NKT) { VMW(8); } else { VMW(0); }
            BAR();
        }
    }

    // epilogue: C/D layout col=lane&31, row=(reg&3)+8*(reg>>2)+4*hi
    // (shape-determined, dtype-independent: m121-m128)
#pragma unroll
    for (int nn = 0; nn < 2; ++nn) {
        const int colg = bCol + wc * 64 + nn * 32 + r32;
        const float yv = y2[colg];
#pragma unroll
        for (int mm = 0; mm < 2; ++mm) {
            const int rbase = bRow + wr * 64 + mm * 32 + 4 * hi;
#pragma unroll
            for (int gq = 0; gq < 4; ++gq) {
                const f32x4 xv = *(const f32x4*)&x2[rbase + 8 * gq];
#pragma unroll
                for (int j = 0; j < 4; ++j) {
                    float sq = fmaxf(xv[j] + yv
                        - 2.0f * acc[mm][nn][gq * 4 + j], 0.0f);
                    out[(size_t)(rbase + 8 * gq + j) * NIMG + colg] =
                        __expf(-sq);
                }
            }
        }
    }
}

extern "C" void kernel_launch(void* const* d_in, const int* in_sizes, int n_in,
                              void* d_out, int out_size, void* d_ws, size_t ws_size,
                              hipStream_t stream) {
    const float* x  = (const float*)d_in[0];
    const float* y  = (const float*)d_in[1];
    const float* cw = (const float*)d_in[2];
    const float* cb = (const float*)d_in[3];
    float* out = (float*)d_out;

    char* ws = (char*)d_ws;
    const size_t featBytes = (size_t)NIMG * KPAD;  // 3.67 MB
    unsigned char* fx = (unsigned char*)ws;
    unsigned char* fy = (unsigned char*)(ws + featBytes);
    float* x2 = (float*)(ws + 2 * featBytes);
    float* y2 = x2 + NIMG;

    feat_kernel<<<2 * NIMG, 256, 0, stream>>>(x, y, cw, cb, fx, fy, x2);

    gram_kernel<<<1024, 256, 0, stream>>>(fx, fy, x2, y2, out);
}